// Round 1
// baseline (1928.783 us; speedup 1.0000x reference)
//
#include <hip/hip_runtime.h>
#include <hip/hip_bf16.h>
#include <stdint.h>

// WTA dropout: per image keep values >= k-th largest (k = ceil(N*0.1)), zero rest.
// Exact selection via 2-stage 16-bit radix select on monotonic float->uint keys.

#define IMGS      32
#define NPER      1048576           // 256*64*64
#define NPER4     (NPER / 4)        // 262144 float4 per image
#define NBINS     65536
#define CAP       65536             // candidate capacity per image (expected ~1.4k)

__device__ __forceinline__ unsigned mapf(float f) {
    unsigned u = __float_as_uint(f);
    // monotonic: larger float <-> larger unsigned
    return (u & 0x80000000u) ? ~u : (u | 0x80000000u);
}

// ---------------- K1: per-image histogram of top 16 key bits ----------------
__global__ void k_hist16(const float4* __restrict__ x4, unsigned* __restrict__ hist,
                         long long n4) {
    long long i = (long long)blockIdx.x * blockDim.x + threadIdx.x;
    long long stride = (long long)gridDim.x * blockDim.x;
    for (; i < n4; i += stride) {
        float4 v = x4[i];
        int img = (int)(i >> 18);            // NPER4 = 2^18
        unsigned* h = hist + (long long)img * NBINS;
        atomicAdd(&h[mapf(v.x) >> 16], 1u);
        atomicAdd(&h[mapf(v.y) >> 16], 1u);
        atomicAdd(&h[mapf(v.z) >> 16], 1u);
        atomicAdd(&h[mapf(v.w) >> 16], 1u);
    }
}

// ---------------- K2: find bin b16 containing k-th largest + rank r ----------
__global__ void k_scan16(const unsigned* __restrict__ hist, uint2* __restrict__ binfo,
                         unsigned k) {
    int img = blockIdx.x;
    const unsigned* h = hist + (long long)img * NBINS;
    __shared__ unsigned sums[256];
    __shared__ unsigned vals[256];
    __shared__ int cstar;
    __shared__ unsigned Abase;
    int t = threadIdx.x;

    unsigned s = 0;
    for (int j = 0; j < 256; ++j) {
        int bin = 65535 - (t * 256 + j);     // descending order chunks
        s += h[bin];
    }
    sums[t] = s;
    __syncthreads();
    if (t == 0) {
        unsigned cum = 0; int c = 0;
        for (; c < 256; ++c) {
            if (cum + sums[c] >= k) break;
            cum += sums[c];
        }
        cstar = c; Abase = cum;
    }
    __syncthreads();
    vals[t] = h[65535 - (cstar * 256 + t)];
    __syncthreads();
    if (t == 0) {
        unsigned cum = Abase;
        for (int j = 0; j < 256; ++j) {
            unsigned hv = vals[j];
            cum += hv;
            if (cum >= k) {
                int bin = 65535 - (cstar * 256 + j);
                binfo[img] = make_uint2((unsigned)bin, k - (cum - hv)); // r in [1,hv]
                break;
            }
        }
    }
}

// ---------------- K3: mask pass + collect boundary-bin candidates ------------
__global__ void k_mask(const float4* __restrict__ x4, float4* __restrict__ o4,
                       const uint2* __restrict__ binfo, unsigned* __restrict__ counters,
                       unsigned* __restrict__ cand, long long n4) {
    long long i = (long long)blockIdx.x * blockDim.x + threadIdx.x;
    long long stride = (long long)gridDim.x * blockDim.x;
    for (; i < n4; i += stride) {
        float4 v = x4[i];
        int img = (int)(i >> 18);
        unsigned b16 = binfo[img].x;
        unsigned base = (unsigned)(i & (NPER4 - 1)) * 4u;  // within-image elem idx
        float4 o;
        float* vp = &v.x;
        float* op = &o.x;
        #pragma unroll
        for (int j = 0; j < 4; ++j) {
            float c = vp[j];
            unsigned t16 = mapf(c) >> 16;
            if (t16 > b16) {
                op[j] = c;
            } else if (t16 < b16) {
                op[j] = 0.0f;
            } else {
                op[j] = c;  // provisional keep; fixed up in K4
                unsigned pos = atomicAdd(&counters[img], 1u);
                if (pos < CAP) cand[(long long)img * CAP + pos] = base + j;
            }
        }
        o4[i] = o;
    }
}

// ---------------- K4: exact low-16 select among candidates + fixup -----------
__global__ void k_select_fix(const float* __restrict__ x, float* __restrict__ out,
                             const uint2* __restrict__ binfo,
                             const unsigned* __restrict__ counters,
                             const unsigned* __restrict__ cand,
                             unsigned* __restrict__ hist2 /* reuse hist1 space */) {
    int img = blockIdx.x;
    const float* xi = x + (long long)img * NPER;
    float* oi = out + (long long)img * NPER;
    unsigned* h = hist2 + (long long)img * NBINS;
    int t = threadIdx.x;

    // zero this image's histogram
    for (int j = t; j < NBINS; j += 256) h[j] = 0u;
    __syncthreads();

    unsigned r = binfo[img].y;
    unsigned cnt = counters[img];
    if (cnt > CAP) cnt = CAP;
    const unsigned* ci = cand + (long long)img * CAP;

    for (unsigned j = t; j < cnt; j += 256) {
        unsigned s = mapf(xi[ci[j]]);
        atomicAdd(&h[s & 0xFFFFu], 1u);
    }
    __syncthreads();

    __shared__ unsigned sums[256];
    __shared__ unsigned vals[256];
    __shared__ int cstar;
    __shared__ unsigned Abase;
    __shared__ unsigned lstar;

    unsigned ssum = 0;
    for (int j = 0; j < 256; ++j) ssum += h[65535 - (t * 256 + j)];
    sums[t] = ssum;
    __syncthreads();
    if (t == 0) {
        unsigned cum = 0; int c = 0;
        for (; c < 256; ++c) {
            if (cum + sums[c] >= r) break;
            cum += sums[c];
        }
        cstar = c; Abase = cum;
    }
    __syncthreads();
    vals[t] = h[65535 - (cstar * 256 + t)];
    __syncthreads();
    if (t == 0) {
        unsigned cum = Abase;
        for (int j = 0; j < 256; ++j) {
            unsigned hv = vals[j];
            cum += hv;
            if (cum >= r) {
                lstar = (unsigned)(65535 - (cstar * 256 + j));
                break;
            }
        }
    }
    __syncthreads();

    unsigned ls = lstar;
    for (unsigned j = t; j < cnt; j += 256) {
        unsigned idx = ci[j];
        unsigned s = mapf(xi[idx]);
        if ((s & 0xFFFFu) < ls) oi[idx] = 0.0f;
    }
}

extern "C" void kernel_launch(void* const* d_in, const int* in_sizes, int n_in,
                              void* d_out, int out_size, void* d_ws, size_t ws_size,
                              hipStream_t stream) {
    const float* x = (const float*)d_in[0];
    float* out = (float*)d_out;
    long long total = in_sizes[0];            // 33,554,432
    long long n4 = total / 4;                 // 8,388,608
    unsigned k = (unsigned)((NPER + 9) / 10); // ceil(N*0.1) = 104858

    // workspace layout
    char* ws = (char*)d_ws;
    unsigned* hist = (unsigned*)ws;                              // 8 MB
    unsigned* counters = (unsigned*)(ws + (size_t)IMGS * NBINS * 4);   // 128 B
    uint2* binfo = (uint2*)(ws + (size_t)IMGS * NBINS * 4 + 128);      // 256 B
    unsigned* cand = (unsigned*)(ws + (size_t)IMGS * NBINS * 4 + 512); // 8 MB

    // zero histogram + counters (ws is NOT re-poisoned between replays)
    hipMemsetAsync(d_ws, 0, (size_t)IMGS * NBINS * 4 + 128, stream);

    dim3 blk(256);
    dim3 grd(2048);
    k_hist16<<<grd, blk, 0, stream>>>((const float4*)x, hist, n4);
    k_scan16<<<dim3(IMGS), blk, 0, stream>>>(hist, binfo, k);
    k_mask<<<grd, blk, 0, stream>>>((const float4*)x, (float4*)out, binfo,
                                    counters, cand, n4);
    k_select_fix<<<dim3(IMGS), blk, 0, stream>>>(x, out, binfo, counters, cand, hist);
}

// Round 2
// 1908.583 us; speedup vs baseline: 1.0106x; 1.0106x over previous
//
#include <hip/hip_runtime.h>
#include <hip/hip_bf16.h>
#include <stdint.h>

// WTA dropout: per image keep values >= k-th largest (k = ceil(N*0.1)), zero rest.
// Exact radix select: 13-bit LDS-privatized histogram, then 3-round in-LDS
// refine (8+8+3 bits) over boundary-bin candidates.

#define IMGS   32
#define NPER   1048576              // 256*64*64 = 2^20
#define NPER4  (NPER / 4)           // 262144 float4 per image = 2^18
#define NBINS  8192                 // 13-bit stage-1 bins
#define BPI    64                   // blocks per image (K1/K3)
#define CAP    16384                // candidate capacity per image (expected ~11k)

__device__ __forceinline__ unsigned mapf(float f) {
    unsigned u = __float_as_uint(f);
    return (u & 0x80000000u) ? ~u : (u | 0x80000000u);   // monotonic float->uint
}

// ---------------- K1: per-image 13-bit histogram, LDS-privatized -------------
__global__ void k_hist(const float4* __restrict__ x4, unsigned* __restrict__ hist) {
    __shared__ unsigned h[NBINS];
    int t = threadIdx.x;
    for (int j = t; j < NBINS; j += 256) h[j] = 0u;
    __syncthreads();

    int bx = blockIdx.x;
    int img = bx >> 6;                          // BPI = 64
    long long base4 = (long long)img * NPER4 + (long long)(bx & 63) * 4096;
    for (int it = 0; it < 16; ++it) {
        float4 v = x4[base4 + it * 256 + t];
        atomicAdd(&h[mapf(v.x) >> 19], 1u);
        atomicAdd(&h[mapf(v.y) >> 19], 1u);
        atomicAdd(&h[mapf(v.z) >> 19], 1u);
        atomicAdd(&h[mapf(v.w) >> 19], 1u);
    }
    __syncthreads();

    unsigned* gh = hist + (long long)img * NBINS;
    for (int j = t; j < NBINS; j += 256) {
        unsigned c = h[j];
        if (c) atomicAdd(&gh[j], c);
    }
}

// ---------------- K2: find stage-1 bin b13 + rank r within it ----------------
__global__ void k_scan(const unsigned* __restrict__ hist, uint2* __restrict__ binfo,
                       unsigned k) {
    int img = blockIdx.x;
    const unsigned* h = hist + (long long)img * NBINS;
    __shared__ unsigned sums[256];
    int t = threadIdx.x;

    unsigned s = 0;
    for (int j = 0; j < 32; ++j) s += h[NBINS - 1 - (t * 32 + j)];  // descending chunks
    sums[t] = s;
    __syncthreads();
    if (t == 0) {
        unsigned cum = 0; int c = 0;
        for (; c < 256; ++c) {
            if (cum + sums[c] >= k) break;
            cum += sums[c];
        }
        for (int j = 0; j < 32; ++j) {
            int bin = NBINS - 1 - (c * 32 + j);
            unsigned hv = h[bin];
            cum += hv;
            if (cum >= k) {
                binfo[img] = make_uint2((unsigned)bin, k - (cum - hv)); // r in [1,hv]
                break;
            }
        }
    }
}

// ---------------- K3: mask pass + collect boundary-bin candidates ------------
__global__ void k_mask(const float4* __restrict__ x4, float4* __restrict__ o4,
                       const uint2* __restrict__ binfo, unsigned* __restrict__ counters,
                       unsigned* __restrict__ candKey, unsigned* __restrict__ candIdx) {
    int bx = blockIdx.x;
    int img = bx >> 6;
    unsigned b13 = binfo[img].x;
    long long base4 = (long long)img * NPER4 + (long long)(bx & 63) * 4096;
    int t = threadIdx.x;
    int lane = t & 63;

    for (int it = 0; it < 16; ++it) {
        long long i = base4 + it * 256 + t;
        float4 v = x4[i];
        unsigned ebase = (unsigned)(i & (NPER4 - 1)) * 4u;
        float4 o;
        float* vp = &v.x;
        float* op = &o.x;
        #pragma unroll
        for (int j = 0; j < 4; ++j) {
            float c = vp[j];
            unsigned key = mapf(c);
            unsigned t13 = key >> 19;
            bool isc = (t13 == b13);
            op[j] = (t13 >= b13) ? c : 0.0f;     // boundary bin: provisional keep
            unsigned long long m = __ballot(isc);
            if (m) {                              // wave-aggregated append
                unsigned base;
                int leader = __ffsll((unsigned long long)m) - 1;
                if (lane == leader)
                    base = atomicAdd(&counters[img], (unsigned)__popcll(m));
                base = __shfl(base, leader);
                if (isc) {
                    unsigned pos = base +
                        (unsigned)__popcll(m & ((1ull << lane) - 1ull));
                    if (pos < CAP) {
                        candKey[(long long)img * CAP + pos] = key;
                        candIdx[(long long)img * CAP + pos] = ebase + (unsigned)j;
                    }
                }
            }
        }
        o4[i] = o;
    }
}

// ------- K4: 3-round LDS radix refine over candidates + exact fixup ----------
__global__ void k_select_fix(float* __restrict__ out,
                             const uint2* __restrict__ binfo,
                             const unsigned* __restrict__ counters,
                             const unsigned* __restrict__ candKey,
                             const unsigned* __restrict__ candIdx) {
    int img = blockIdx.x;
    __shared__ unsigned h[256];
    __shared__ unsigned sh_prefix, sh_r;
    int t = threadIdx.x;

    unsigned cnt = counters[img];
    if (cnt > CAP) cnt = CAP;
    unsigned r = binfo[img].y;
    const unsigned* ck = candKey + (long long)img * CAP;
    const unsigned* ci = candIdx + (long long)img * CAP;

    unsigned prefix = 0;
    const int shifts[3] = {11, 3, 0};
    const int widths[3] = {8, 8, 3};
    for (int rd = 0; rd < 3; ++rd) {
        h[t] = 0u;
        __syncthreads();
        int shift = shifts[rd], width = widths[rd];
        unsigned topshift = (unsigned)(shift + width);
        unsigned bmask = (1u << width) - 1u;
        for (unsigned j = t; j < cnt; j += 256u) {
            unsigned kl = ck[j] & 0x7FFFFu;           // low 19 bits
            if ((kl >> topshift) == prefix)
                atomicAdd(&h[(kl >> shift) & bmask], 1u);
        }
        __syncthreads();
        if (t == 0) {
            unsigned cum = 0;
            for (int b = (int)bmask; b >= 0; --b) {
                unsigned hv = h[b];
                cum += hv;
                if (cum >= r) {
                    sh_prefix = (prefix << width) | (unsigned)b;
                    sh_r = r - (cum - hv);
                    break;
                }
            }
        }
        __syncthreads();
        prefix = sh_prefix;
        r = sh_r;
    }

    unsigned thr = prefix;                            // exact low-19 bits of k-th largest
    float* oi = out + (long long)img * NPER;
    for (unsigned j = t; j < cnt; j += 256u) {
        if ((ck[j] & 0x7FFFFu) < thr) oi[ci[j]] = 0.0f;
    }
}

extern "C" void kernel_launch(void* const* d_in, const int* in_sizes, int n_in,
                              void* d_out, int out_size, void* d_ws, size_t ws_size,
                              hipStream_t stream) {
    const float* x = (const float*)d_in[0];
    float* out = (float*)d_out;
    unsigned k = (unsigned)((NPER + 9) / 10);         // ceil(N*0.1) = 104858

    // workspace layout (well under previous 16.5 MB usage)
    char* ws = (char*)d_ws;
    unsigned* hist     = (unsigned*)ws;                               // 1 MB
    unsigned* counters = (unsigned*)(ws + (size_t)IMGS * NBINS * 4);  // 128 B
    uint2*    binfo    = (uint2*)   (ws + (size_t)IMGS * NBINS * 4 + 128);
    unsigned* candKey  = (unsigned*)(ws + (size_t)IMGS * NBINS * 4 + 512);        // 2 MB
    unsigned* candIdx  = (unsigned*)(ws + (size_t)IMGS * NBINS * 4 + 512
                                        + (size_t)IMGS * CAP * 4);                // 2 MB

    // zero hist + counters each call (ws is not re-poisoned between replays)
    hipMemsetAsync(d_ws, 0, (size_t)IMGS * NBINS * 4 + 128, stream);

    dim3 blk(256);
    k_hist<<<dim3(IMGS * BPI), blk, 0, stream>>>((const float4*)x, hist);
    k_scan<<<dim3(IMGS), blk, 0, stream>>>(hist, binfo, k);
    k_mask<<<dim3(IMGS * BPI), blk, 0, stream>>>((const float4*)x, (float4*)out,
                                                 binfo, counters, candKey, candIdx);
    k_select_fix<<<dim3(IMGS), blk, 0, stream>>>(out, binfo, counters, candKey, candIdx);
}

// Round 3
// 153.298 us; speedup vs baseline: 12.5819x; 12.4502x over previous
//
#include <hip/hip_runtime.h>
#include <hip/hip_bf16.h>
#include <stdint.h>

// WTA dropout: per image keep values >= k-th largest (k = ceil(N*0.1)), zero rest.
// Exact radix select: 13-bit LDS-privatized histogram, 3-round LDS refine over
// boundary-bin candidates. Candidate collection is block-local (LDS) with ONE
// global atomic per block -- the per-line counter contention was 1.8ms (round 2).

#define IMGS    32
#define NPER    1048576             // 2^20 elements per image
#define NPER4   (NPER / 4)          // 2^18 float4 per image
#define NBINS   8192                // 13-bit stage-1 bins
#define BPI_H   16                  // blocks per image, hist kernel
#define BPI_M   64                  // blocks per image, mask kernel
#define CAP     16384               // global candidate capacity per image (~11.5k expected)
#define LCAP    2048                // per-block LDS candidate capacity (~180 expected)
#define CSTRIDE 64                  // counters padded to 256 B apart

__device__ __forceinline__ unsigned mapf(float f) {
    unsigned u = __float_as_uint(f);
    return (u & 0x80000000u) ? ~u : (u | 0x80000000u);   // monotonic float->uint
}

// ---------------- K1: per-image 13-bit histogram, LDS-privatized -------------
__global__ void k_hist(const float4* __restrict__ x4, unsigned* __restrict__ hist) {
    __shared__ unsigned h[NBINS];
    int t = threadIdx.x;
    for (int j = t; j < NBINS; j += 256) h[j] = 0u;
    __syncthreads();

    int bx = blockIdx.x;
    int img = bx >> 4;                          // BPI_H = 16
    long long base4 = (long long)img * NPER4 + (long long)(bx & 15) * 16384;
    for (int it = 0; it < 64; ++it) {
        float4 v = x4[base4 + it * 256 + t];
        atomicAdd(&h[mapf(v.x) >> 19], 1u);
        atomicAdd(&h[mapf(v.y) >> 19], 1u);
        atomicAdd(&h[mapf(v.z) >> 19], 1u);
        atomicAdd(&h[mapf(v.w) >> 19], 1u);
    }
    __syncthreads();

    unsigned* gh = hist + (long long)img * NBINS;
    for (int j = t; j < NBINS; j += 256) {
        unsigned c = h[j];
        if (c) atomicAdd(&gh[j], c);
    }
}

// ---------------- K2: find stage-1 bin b13 + rank r within it ----------------
__global__ void k_scan(const unsigned* __restrict__ hist, uint2* __restrict__ binfo,
                       unsigned k) {
    int img = blockIdx.x;
    const unsigned* h = hist + (long long)img * NBINS;
    __shared__ unsigned sums[256];
    int t = threadIdx.x;

    unsigned s = 0;
    for (int j = 0; j < 32; ++j) s += h[NBINS - 1 - (t * 32 + j)];  // descending chunks
    sums[t] = s;
    __syncthreads();
    if (t == 0) {
        unsigned cum = 0; int c = 0;
        for (; c < 256; ++c) {
            if (cum + sums[c] >= k) break;
            cum += sums[c];
        }
        for (int j = 0; j < 32; ++j) {
            int bin = NBINS - 1 - (c * 32 + j);
            unsigned hv = h[bin];
            cum += hv;
            if (cum >= k) {
                binfo[img] = make_uint2((unsigned)bin, k - (cum - hv)); // r in [1,hv]
                break;
            }
        }
    }
}

// -------- K3: mask pass + LDS-staged boundary-bin candidate collection -------
__global__ void k_mask(const float4* __restrict__ x4, float4* __restrict__ o4,
                       const uint2* __restrict__ binfo, unsigned* __restrict__ counters,
                       unsigned* __restrict__ candKey, unsigned* __restrict__ candIdx) {
    __shared__ unsigned lkey[LCAP];
    __shared__ unsigned lidx[LCAP];
    __shared__ unsigned lcnt;
    __shared__ unsigned gbase;
    int t = threadIdx.x;
    if (t == 0) lcnt = 0u;
    __syncthreads();

    int bx = blockIdx.x;
    int img = bx >> 6;                          // BPI_M = 64
    unsigned b13 = binfo[img].x;
    long long base4 = (long long)img * NPER4 + (long long)(bx & 63) * 4096;

    for (int it = 0; it < 16; ++it) {
        long long i = base4 + it * 256 + t;
        float4 v = x4[i];
        unsigned ebase = (unsigned)(i & (NPER4 - 1)) * 4u;
        float4 o;
        float* vp = &v.x;
        float* op = &o.x;
        #pragma unroll
        for (int j = 0; j < 4; ++j) {
            float c = vp[j];
            unsigned key = mapf(c);
            unsigned t13 = key >> 19;
            op[j] = (t13 >= b13) ? c : 0.0f;     // boundary bin: provisional keep
            if (t13 == b13) {
                unsigned p = atomicAdd(&lcnt, 1u);   // LDS atomic: cheap
                if (p < LCAP) { lkey[p] = key; lidx[p] = ebase + (unsigned)j; }
            }
        }
        o4[i] = o;
    }
    __syncthreads();

    unsigned n = lcnt;
    if (n > LCAP) n = LCAP;
    if (t == 0) gbase = atomicAdd(&counters[img * CSTRIDE], n);  // ONE per block
    __syncthreads();
    unsigned gb = gbase;
    long long cb = (long long)img * CAP;
    for (unsigned j = t; j < n; j += 256u) {
        unsigned pos = gb + j;
        if (pos < CAP) {
            candKey[cb + pos] = lkey[j];
            candIdx[cb + pos] = lidx[j];
        }
    }
}

// ------- K4: 3-round LDS radix refine over candidates + exact fixup ----------
__global__ void k_select_fix(float* __restrict__ out,
                             const uint2* __restrict__ binfo,
                             const unsigned* __restrict__ counters,
                             const unsigned* __restrict__ candKey,
                             const unsigned* __restrict__ candIdx) {
    int img = blockIdx.x;
    __shared__ unsigned h[256];
    __shared__ unsigned sh_prefix, sh_r;
    int t = threadIdx.x;

    unsigned cnt = counters[img * CSTRIDE];
    if (cnt > CAP) cnt = CAP;
    unsigned r = binfo[img].y;
    const unsigned* ck = candKey + (long long)img * CAP;
    const unsigned* ci = candIdx + (long long)img * CAP;

    unsigned prefix = 0;
    const int shifts[3] = {11, 3, 0};
    const int widths[3] = {8, 8, 3};
    for (int rd = 0; rd < 3; ++rd) {
        h[t] = 0u;
        __syncthreads();
        int shift = shifts[rd], width = widths[rd];
        unsigned topshift = (unsigned)(shift + width);
        unsigned bmask = (1u << width) - 1u;
        for (unsigned j = t; j < cnt; j += 256u) {
            unsigned kl = ck[j] & 0x7FFFFu;           // low 19 bits
            if ((kl >> topshift) == prefix)
                atomicAdd(&h[(kl >> shift) & bmask], 1u);
        }
        __syncthreads();
        if (t == 0) {
            unsigned cum = 0;
            for (int b = (int)bmask; b >= 0; --b) {
                unsigned hv = h[b];
                cum += hv;
                if (cum >= r) {
                    sh_prefix = (prefix << width) | (unsigned)b;
                    sh_r = r - (cum - hv);
                    break;
                }
            }
        }
        __syncthreads();
        prefix = sh_prefix;
        r = sh_r;
    }

    unsigned thr = prefix;                            // exact low-19 bits of k-th largest
    float* oi = out + (long long)img * NPER;
    for (unsigned j = t; j < cnt; j += 256u) {
        if ((ck[j] & 0x7FFFFu) < thr) oi[ci[j]] = 0.0f;
    }
}

extern "C" void kernel_launch(void* const* d_in, const int* in_sizes, int n_in,
                              void* d_out, int out_size, void* d_ws, size_t ws_size,
                              hipStream_t stream) {
    const float* x = (const float*)d_in[0];
    float* out = (float*)d_out;
    unsigned k = (unsigned)((NPER + 9) / 10);         // ceil(N*0.1) = 104858

    // workspace layout
    char* ws = (char*)d_ws;
    size_t histB = (size_t)IMGS * NBINS * 4;                         // 1 MB
    size_t cntB  = (size_t)IMGS * CSTRIDE * 4;                       // 8 KB
    unsigned* hist     = (unsigned*)ws;
    unsigned* counters = (unsigned*)(ws + histB);
    uint2*    binfo    = (uint2*)   (ws + histB + cntB);
    unsigned* candKey  = (unsigned*)(ws + histB + cntB + 1024);      // 2 MB
    unsigned* candIdx  = (unsigned*)(ws + histB + cntB + 1024
                                        + (size_t)IMGS * CAP * 4);   // 2 MB

    // zero hist + counters each call (ws is not re-poisoned between replays)
    hipMemsetAsync(d_ws, 0, histB + cntB, stream);

    dim3 blk(256);
    k_hist<<<dim3(IMGS * BPI_H), blk, 0, stream>>>((const float4*)x, hist);
    k_scan<<<dim3(IMGS), blk, 0, stream>>>(hist, binfo, k);
    k_mask<<<dim3(IMGS * BPI_M), blk, 0, stream>>>((const float4*)x, (float4*)out,
                                                   binfo, counters, candKey, candIdx);
    k_select_fix<<<dim3(IMGS), blk, 0, stream>>>(out, binfo, counters, candKey, candIdx);
}